// Round 13
// baseline (224.579 us; speedup 1.0000x reference)
//
#include <hip/hip_runtime.h>
#include <hip/hip_bf16.h>
#include <stdint.h>

// Problem dims (fixed)
#define Bc 2
#define Sc 2048
#define Dc 1024
#define Hc 16
#define Fc 64
constexpr int BHSF = Bc * Hc * Sc * Fc;   // 4,194,304

typedef __attribute__((ext_vector_type(8))) short bf16x8;   // MFMA A/B frag (4 VGPR)
typedef __attribute__((ext_vector_type(4))) float f32x4;    // MFMA C/D frag

#define MFMA16(a, b, c) __builtin_amdgcn_mfma_f32_16x16x32_bf16(a, b, c, 0, 0, 0)
#define EXP2(x) __builtin_amdgcn_exp2f(x)
#define SCALE2 0.18033688f   /* 0.125 * log2(e); Q is PRE-SCALED by this in proj */

__device__ inline short f2bfn(float x) {          // native RNE fp32->bf16
    __hip_bfloat16 h = __float2bfloat16(x);
    return __builtin_bit_cast(short, h);
}
__device__ inline uint32_t cvt2(float lo, float hi) {   // packed bf16 pair
    uint32_t a = (uint16_t)f2bfn(lo);
    uint32_t b = (uint16_t)f2bfn(hi);
    return a | (b << 16);          // compiler fuses to v_cvt_pk_bf16_f32
}
__device__ inline float bf2f(short s) {
    uint32_t u = ((uint32_t)(uint16_t)s) << 16;
    return __builtin_bit_cast(float, u);
}

// async global->LDS, 16B per lane. LDS dest = wave-uniform base + lane*16 (m104);
// global src is per-lane. AS3 pointer = low 32 bits of the flat LDS address.
__device__ inline void dma16(const short* g, short* l) {
    __builtin_amdgcn_global_load_lds(
        (const __attribute__((address_space(1))) void*)g,
        (__attribute__((address_space(3))) void*)(uintptr_t)(uint32_t)(uintptr_t)l,
        16, 0, 0);
}

// ---------------------------------------------------------------------------
// K0a: elementwise fp32 -> bf16 for q,k,v into Xb[3][4096][1024]
// grid (1024, 3), 256 thr, 16 elems/thr.
// ---------------------------------------------------------------------------
__global__ __launch_bounds__(256) void xcvt_kernel(
    const float* __restrict__ a, const float* __restrict__ b,
    const float* __restrict__ c, short* __restrict__ out)
{
    const float* src = (blockIdx.y == 0) ? a : (blockIdx.y == 1) ? b : c;
    const size_t base = (size_t)blockIdx.x * 4096 + threadIdx.x * 16;
    const float* s = src + base;
    short* d = out + (size_t)blockIdx.y * 4096 * 1024 + base;
    f32x4 v0 = ((const f32x4*)s)[0], v1 = ((const f32x4*)s)[1];
    f32x4 v2 = ((const f32x4*)s)[2], v3 = ((const f32x4*)s)[3];
    bf16x8 p0, p1;
    #pragma unroll
    for (int i = 0; i < 4; ++i) {
        p0[i] = f2bfn(v0[i]); p0[4 + i] = f2bfn(v1[i]);
        p1[i] = f2bfn(v2[i]); p1[4 + i] = f2bfn(v3[i]);
    }
    *(bf16x8*)d       = p0;
    *(bf16x8*)(d + 8) = p1;
}

// ---------------------------------------------------------------------------
// K0b: ALL weight transposes+cvt in one kernel.
// z < 48: QKV weights (sel = z>>4, h = z&15): [1024][64] f32 -> [64][1024] bf16
// z >= 48: Wo col-strip n0 = (z-48)*64:       [1024][1024]  -> [1024][1024]
// grid (16, 1, 64), 256 thr.
// ---------------------------------------------------------------------------
__global__ __launch_bounds__(256) void tcvt_all_kernel(
    const float* __restrict__ Wq, const float* __restrict__ Wk,
    const float* __restrict__ Wv, const float* __restrict__ Wo,
    short* __restrict__ WqT, short* __restrict__ WkT,
    short* __restrict__ WvT, short* __restrict__ WoT)
{
    __shared__ short td[64 * 72];
    const int t = threadIdx.x;
    const int sr = t >> 2, sc = (t & 3) * 16;
    const int zp = blockIdx.z;
    const int m0 = blockIdx.x * 64;

    const float* in; short* out; int N, n0;
    if (zp < 48) {
        const int sel = zp >> 4, h = zp & 15;
        in  = ((sel == 0) ? Wq : (sel == 1) ? Wk : Wv) + (size_t)h * Dc * Fc;
        out = ((sel == 0) ? WqT : (sel == 1) ? WkT : WvT) + (size_t)h * Fc * Dc;
        N = Fc; n0 = 0;
    } else {
        in = Wo; out = WoT; N = Dc; n0 = (zp - 48) * 64;
    }

    const float* src = in + (size_t)(m0 + sr) * N + n0 + sc;
    #pragma unroll
    for (int i = 0; i < 16; i += 4) {
        f32x4 a = *(const f32x4*)(src + i);
        td[sr * 72 + sc + i + 0] = f2bfn(a[0]);
        td[sr * 72 + sc + i + 1] = f2bfn(a[1]);
        td[sr * 72 + sc + i + 2] = f2bfn(a[2]);
        td[sr * 72 + sc + i + 3] = f2bfn(a[3]);
    }
    __syncthreads();
    alignas(16) short vals[16];
    #pragma unroll
    for (int i = 0; i < 16; ++i) vals[i] = td[(sc + i) * 72 + sr];
    short* dst = out + (size_t)(n0 + sr) * Dc + m0 + sc;
    *(bf16x8*)dst       = *(const bf16x8*)&vals[0];
    *(bf16x8*)(dst + 8) = *(const bf16x8*)&vals[8];
}

// ---------------------------------------------------------------------------
// K1: QKV projection from bf16 Xb, m97-style staging via global_load_lds,
// LINEAR [128][32] LDS tiles, double-buffered, BK=32. [r11 verbatim]
// grid (32 mt, 8 hp, 3 z), mt fastest (XCD-share of x slab).
// ---------------------------------------------------------------------------
__global__ __launch_bounds__(256) void proj_kernel(
    const short* __restrict__ Xb,
    const short* __restrict__ WqT, const short* __restrict__ WkT,
    const short* __restrict__ WvT,
    short* __restrict__ Qo, short* __restrict__ Ko, short* __restrict__ VtO)
{
    const int mt = blockIdx.x, hp = blockIdx.y, z = blockIdx.z;
    const short* X  = Xb + (size_t)z * 4096 * Dc;
    const short* Wt = ((z == 0) ? WqT : (z == 1) ? WkT : WvT) + (size_t)hp * 128 * Dc;
    const int m0 = mt * 128;

    // per buf: [0,4096) = x[128][32], [4096,8192) = w[128][32]  (32 KB total)
    __shared__ short sm[2][8192];

    const int t = threadIdx.x, lane = t & 63, w = t >> 6;
    const int wm = w >> 1, wn = w & 1;
    const int l15 = lane & 15, g = lane >> 4;
    const int lr = lane >> 2, lc = (lane & 3) * 8;   // DMA lane map (16 rows/instr)

    auto issue = [&](int buf, int d0) {
        #pragma unroll
        for (int i = 0; i < 2; ++i) {
            const int rr = (w * 2 + i) * 16 + lr;
            dma16(&X [(size_t)(m0 + rr) * Dc + d0 + lc],
                  &sm[buf][(w * 2 + i) * 512]);
            dma16(&Wt[(size_t)rr        * Dc + d0 + lc],
                  &sm[buf][4096 + (w * 2 + i) * 512]);
        }
    };

    f32x4 acc[4][4];
    #pragma unroll
    for (int i = 0; i < 4; ++i)
        #pragma unroll
        for (int j = 0; j < 4; ++j) acc[i][j] = (f32x4){0.f, 0.f, 0.f, 0.f};

    issue(0, 0);

    for (int d0 = 0; d0 < Dc; d0 += 32) {
        const int cur = (d0 >> 5) & 1;
        __syncthreads();                      // buf[cur] DMA complete
        if (d0 + 32 < Dc) issue(cur ^ 1, d0 + 32);   // in flight across compute
        const short* xb = &sm[cur][0];
        const short* wb = &sm[cur][4096];
        bf16x8 afr[4], bfr[4];
        #pragma unroll
        for (int ms = 0; ms < 4; ++ms)
            afr[ms] = *(const bf16x8*)&xb[(wm * 64 + ms * 16 + l15) * 32 + g * 8];
        #pragma unroll
        for (int fb = 0; fb < 4; ++fb)
            bfr[fb] = *(const bf16x8*)&wb[(wn * 64 + fb * 16 + l15) * 32 + g * 8];
        #pragma unroll
        for (int ms = 0; ms < 4; ++ms)
            #pragma unroll
            for (int fb = 0; fb < 4; ++fb)
                acc[ms][fb] = MFMA16(afr[ms], bfr[fb], acc[ms][fb]);
    }

    // Epilogue: 2 passes through an 18KB bounce overlaid on sm (flat view).
    short* ob = &sm[0][0];                    // [128][72]
    const float oscale = (z == 0) ? SCALE2 : 1.0f;
    const int b = m0 >> 11, s0 = m0 & 2047;
    #pragma unroll
    for (int p = 0; p < 2; ++p) {
        __syncthreads();                      // ob free
        if (wn == p) {
            #pragma unroll
            for (int ms = 0; ms < 4; ++ms)
                #pragma unroll
                for (int fb = 0; fb < 4; ++fb)
                    #pragma unroll
                    for (int r = 0; r < 4; ++r)
                        ob[(wm * 64 + ms * 16 + g * 4 + r) * 72 + fb * 16 + l15] =
                            f2bfn(acc[ms][fb][r] * oscale);
        }
        __syncthreads();
        const int h = hp * 2 + p;
        if (z < 2) {
            const int row = t >> 1, c0 = (t & 1) * 32;
            short* outp = ((z == 0) ? Qo : Ko)
                        + ((size_t)(b * Hc + h) * Sc + s0 + row) * Fc + c0;
            #pragma unroll
            for (int j = 0; j < 32; j += 8)
                *(bf16x8*)&outp[j] = *(const bf16x8*)&ob[row * 72 + c0 + j];
        } else {
            const int f = t >> 2, cg = (t & 3) * 32;
            short* o = VtO + ((size_t)(b * Hc + h) * Fc + f) * Sc + s0 + cg;
            alignas(16) short vals[32];
            #pragma unroll
            for (int j = 0; j < 32; ++j) vals[j] = ob[(cg + j) * 72 + f];
            #pragma unroll
            for (int j = 0; j < 32; j += 8)
                *(bf16x8*)(o + j) = *(const bf16x8*)&vals[j];
        }
    }
}

// ---------------------------------------------------------------------------
// K2: softmax denom [r12 verbatim]. NO max tracking; l = sum exp2(s');
// writes m' = log2(l). Single-barrier dbuf K staging. bh fastest (XCD).
// grid (32 bh, 16 qt), 256 thr.
// ---------------------------------------------------------------------------
__global__ __launch_bounds__(256) void stats_kernel(
    const short* __restrict__ Qg, const short* __restrict__ Kg,
    float* __restrict__ mrow)
{
    const int bh = blockIdx.x;
    const int q0 = blockIdx.y * 128;
    const short* Qb = Qg + (size_t)bh * Sc * Fc;
    const short* Kb = Kg + (size_t)bh * Sc * Fc;

    __shared__ short ksA[64 * 72], ksB[64 * 72];

    const int t = threadIdx.x, lane = t & 63, w = t >> 6;
    const int l15 = lane & 15, g = lane >> 4;
    const int sr4 = t >> 2, sc4 = (t & 3) * 16;

    bf16x8 qf[2][2];
    #pragma unroll
    for (int qs2 = 0; qs2 < 2; ++qs2)
        #pragma unroll
        for (int kc2 = 0; kc2 < 2; ++kc2)
            qf[qs2][kc2] = *(const bf16x8*)
                &Qb[(size_t)(q0 + w * 32 + qs2 * 16 + l15) * Fc + kc2 * 32 + g * 8];

    bf16x8 kr0, kr1;
    auto gload = [&](int kt) {
        const short* s = &Kb[(size_t)(kt + sr4) * Fc + sc4];
        kr0 = *(const bf16x8*)s;
        kr1 = *(const bf16x8*)(s + 8);
    };
    auto swrite = [&](short* d) {
        *(bf16x8*)&d[sr4 * 72 + sc4]     = kr0;
        *(bf16x8*)&d[sr4 * 72 + sc4 + 8] = kr1;
    };

    f32x4 ls[2];
    ls[0] = (f32x4){0.f, 0.f, 0.f, 0.f};
    ls[1] = (f32x4){0.f, 0.f, 0.f, 0.f};

    gload(0); swrite(ksA); gload(64);

    auto half = [&](int kt, const short* cur, short* nxt) {
        __syncthreads();
        if (kt + 64 < Sc) swrite(nxt);
        if (kt + 128 < Sc) gload(kt + 128);
        #pragma unroll
        for (int kf = 0; kf < 4; ++kf) {
            bf16x8 a0 = *(const bf16x8*)&cur[(kf * 16 + l15) * 72 + 0  + g * 8];
            bf16x8 a1 = *(const bf16x8*)&cur[(kf * 16 + l15) * 72 + 32 + g * 8];
            #pragma unroll
            for (int qs2 = 0; qs2 < 2; ++qs2) {
                f32x4 acc = (f32x4){0.f, 0.f, 0.f, 0.f};
                acc = MFMA16(a0, qf[qs2][0], acc);
                acc = MFMA16(a1, qf[qs2][1], acc);   // same d-split order as attn
                #pragma unroll
                for (int r = 0; r < 4; ++r) ls[qs2][r] += EXP2(acc[r]);
            }
        }
    };

    for (int kt = 0; kt < Sc; kt += 128) {
        half(kt,      ksA, ksB);
        half(kt + 64, ksB, ksA);
    }

    #pragma unroll
    for (int qs2 = 0; qs2 < 2; ++qs2) {
        float l = (ls[qs2][0] + ls[qs2][1]) + (ls[qs2][2] + ls[qs2][3]);
        l += __shfl_xor(l, 16, 64);
        l += __shfl_xor(l, 32, 64);
        if (lane < 16)
            mrow[bh * Sc + q0 + w * 32 + qs2 * 16 + l15] = __log2f(l);
    }
}

// ---------------------------------------------------------------------------
// K3: attention — LDS-diet version. Q-frags, Vt-frags and m' come DIRECTLY
// from global (L2-resident per XCD: r12 measured FETCH 12.5 MB), prefetched
// ONE FULL CHUNK ahead into named register double-buffers (static indices
// only). Only P^T lives in LDS (per-wave private rows, r12-validated).
// -> ZERO barriers and ZERO LDS staging in the main loop; LDS bytes/wave-chunk
// drop 40KB -> 16KB (the r12 bottleneck at ~78% LDS-pipe busy).
// grid (32 bh, 2 qh, 8 kt), 256 thr / 4 waves, launch_bounds(256,2).
// ---------------------------------------------------------------------------
__global__ __launch_bounds__(256, 2) void attn_kernel(
    const short* __restrict__ Qg, const short* __restrict__ Kg,
    const short* __restrict__ VtG, const float* __restrict__ mrow,
    short* __restrict__ O4a, short* __restrict__ O4b)
{
    const int bh = blockIdx.x;
    const int qh = blockIdx.y;
    const int k0 = blockIdx.z * 256;
    const int qbeg = qh * 1024, qend = qbeg + 1024;
    const short* Qb = Qg  + (size_t)bh * Sc * Fc;
    const short* Kb = Kg  + (size_t)bh * Sc * Fc;
    const short* Vb = VtG + (size_t)bh * Fc * Sc;   // [64 f][2048 s]
    const float* mb = mrow + (size_t)bh * Sc;

    __shared__ short pl[4][64 * 72];   // P^T, per-wave PRIVATE; out-bounce at end

    const int t = threadIdx.x, lane = t & 63, w = t >> 6;   // w 0..3
    const int l15 = lane & 15, g = lane >> 4;
    short* plw = &pl[w][0];

    // resident K B-frags: wave w owns k-cols k0 + w*64 + ks*16 + l15
    bf16x8 kf[4][2];
    #pragma unroll
    for (int ks = 0; ks < 4; ++ks)
        #pragma unroll
        for (int kc = 0; kc < 2; ++kc)
            kf[ks][kc] = *(const bf16x8*)
                &Kb[(size_t)(k0 + w * 64 + ks * 16 + l15) * Fc + kc * 32 + g * 8];

    // per-lane global fragment bases (16 rows x 64B fully-used lines)
    const short* qbase = Qb + (size_t)l15 * Fc + g * 8;
    const short* vbase = Vb + (size_t)l15 * Sc + g * 8;

    f32x4 oacc[4][4];
    #pragma unroll
    for (int i = 0; i < 4; ++i)
        #pragma unroll
        for (int j = 0; j < 4; ++j) oacc[i][j] = (f32x4){0.f, 0.f, 0.f, 0.f};

    bf16x8 qa[4][2], qaN[4][2];      // Q A-frags, chunk double-buffer
    bf16x8 vf[2][4], vfN[2][4];      // Vt B-frags
    f32x4  mq[4],    mqN[4];         // fused m' per q-row quad

    auto loadQ = [&](int q0, bf16x8 (&dq)[4][2], f32x4 (&dm)[4]) {
        #pragma unroll
        for (int qf = 0; qf < 4; ++qf) {
            const short* s = qbase + (size_t)(q0 + qf * 16) * Fc;
            dq[qf][0] = *(const bf16x8*)s;
            dq[qf][1] = *(const bf16x8*)(s + 32);
            dm[qf] = *(const f32x4*)&mb[q0 + qf * 16 + g * 4];
        }
    };
    auto loadV = [&](int q0, bf16x8 (&dv)[2][4]) {
        #pragma unroll
        for (int c = 0; c < 2; ++c)
            #pragma unroll
            for (int fb = 0; fb < 4; ++fb)
                dv[c][fb] = *(const bf16x8*)
                    (vbase + (size_t)fb * 16 * Sc + q0 + c * 32);
    };

    loadQ(qbeg, qa, mq);
    loadV(qbeg, vf);

    for (int q0 = qbeg; q0 < qend; q0 += 64) {
        // issue next chunk's loads NOW — ~2000 cyc of compute covers L2 latency
        if (q0 + 64 < qend) { loadQ(q0 + 64, qaN, mqN); loadV(q0 + 64, vfN); }

        // phase A: S = mfma(Q,K); C row=q (qf*16+g*4+r), col=k (w*64+ks*16+l15)
        #pragma unroll
        for (int qf = 0; qf < 4; ++qf) {
            #pragma unroll
            for (int ks = 0; ks < 4; ++ks) {
                f32x4 acc = (f32x4){0.f, 0.f, 0.f, 0.f};
                acc = MFMA16(qa[qf][0], kf[ks][0], acc);
                acc = MFMA16(qa[qf][1], kf[ks][1], acc);
                uint2 pv;
                pv.x = cvt2(EXP2(acc[0] - mq[qf][0]), EXP2(acc[1] - mq[qf][1]));
                pv.y = cvt2(EXP2(acc[2] - mq[qf][2]), EXP2(acc[3] - mq[qf][3]));
                *(uint2*)&plw[(ks * 16 + l15) * 72 + qf * 16 + g * 4] = pv;
            }
        }
        // NO barrier: pl rows are private to this wave (wave-internal lgkmcnt).

        // phase B: PV.  A = own P^T rows (LDS), B = Vt frags (registers).
        #pragma unroll
        for (int qc = 0; qc < 2; ++qc) {
            bf16x8 pa[4];
            #pragma unroll
            for (int ks = 0; ks < 4; ++ks)
                pa[ks] = *(const bf16x8*)&plw[(ks * 16 + l15) * 72 + qc * 32 + g * 8];
            #pragma unroll
            for (int ks = 0; ks < 4; ++ks)
                #pragma unroll
                for (int fb = 0; fb < 4; ++fb)
                    oacc[ks][fb] = MFMA16(pa[ks], vf[qc][fb], oacc[ks][fb]);
        }

        // rotate prefetch buffers (all-static indices -> stays in registers)
        if (q0 + 64 < qend) {
            #pragma unroll
            for (int qf = 0; qf < 4; ++qf) {
                qa[qf][0] = qaN[qf][0];
                qa[qf][1] = qaN[qf][1];
                mq[qf]    = mqN[qf];
            }
            #pragma unroll
            for (int c = 0; c < 2; ++c)
                #pragma unroll
                for (int fb = 0; fb < 4; ++fb)
                    vf[c][fb] = vfN[c][fb];
        }
    }

    // epilogue: bounce via pl (flat 256 rows x 64) for coalesced bf16 stores
    __syncthreads();
    #pragma unroll
    for (int ks = 0; ks < 4; ++ks)
        #pragma unroll
        for (int fb = 0; fb < 4; ++fb)
            #pragma unroll
            for (int r = 0; r < 4; ++r)
                plw[(ks * 16 + g * 4 + r) * 72 + fb * 16 + l15] =
                    f2bfn(oacc[ks][fb][r]);
    __syncthreads();
    {
        const short* plf = &pl[0][0];
        short* O = qh ? O4b : O4a;
        short* o = O + ((size_t)bh * Sc + k0 + t) * Fc;
        #pragma unroll
        for (int j = 0; j < 64; j += 8)
            *(bf16x8*)&o[j] = *(const bf16x8*)&plf[t * 72 + j];
    }
}

// ---------------------------------------------------------------------------
// K4: out(fp32) = (O4a + O4b) @ Wo [r12 verbatim]. NT, dbuf, partial-sum in
// A-staging. m-tile 128 (msub=2). grid (32, 16), 256 thr.
// ---------------------------------------------------------------------------
__global__ __launch_bounds__(256) void outgemm_kernel(
    const short* __restrict__ Aa, const short* __restrict__ Ab,
    const short* __restrict__ WoT, float* __restrict__ out)
{
    const int m0 = blockIdx.x * 128, n0 = blockIdx.y * 64;

    __shared__ short asA[128 * 72], asB[128 * 72];
    __shared__ short wsA[64 * 72],  wsB[64 * 72];

    const int t = threadIdx.x, lane = t & 63, w = t >> 6;
    const int l15 = lane & 15, g = lane >> 4;
    const int ar = t >> 1, ac = (t & 1) * 32;
    const int wr = t >> 2, wc = (t & 3) * 16;

    bf16x8 ag0[4], ag1[4], wg[2];
    auto gload = [&](int d0) {
        const short* s0 = &Aa[(size_t)(m0 + ar) * Dc + d0 + ac];
        const short* s1 = &Ab[(size_t)(m0 + ar) * Dc + d0 + ac];
        #pragma unroll
        for (int j = 0; j < 4; ++j) { ag0[j] = *(const bf16x8*)(s0 + 8 * j);
                                      ag1[j] = *(const bf16x8*)(s1 + 8 * j); }
        const short* ww = &WoT[(size_t)(n0 + wr) * Dc + d0 + wc];
        wg[0] = *(const bf16x8*)ww;
        wg[1] = *(const bf16x8*)(ww + 8);
    };
    auto swrite = [&](short* asD, short* wsD) {
        #pragma unroll
        for (int j = 0; j < 4; ++j) {
            bf16x8 r;
            #pragma unroll
            for (int i = 0; i < 8; ++i)
                r[i] = f2bfn(bf2f(ag0[j][i]) + bf2f(ag1[j][i]));
            *(bf16x8*)&asD[ar * 72 + ac + 8 * j] = r;
        }
        *(bf16x8*)&wsD[wr * 72 + wc]     = wg[0];
        *(bf16x8*)&wsD[wr * 72 + wc + 8] = wg[1];
    };

    f32x4 acc[2][4];
    #pragma unroll
    for (int i = 0; i < 2; ++i)
        #pragma unroll
        for (int j = 0; j < 4; ++j) acc[i][j] = (f32x4){0.f, 0.f, 0.f, 0.f};

    gload(0); swrite(asA, wsA); gload(64);

    auto half = [&](int d0, const short* asC, const short* wsC,
                    short* asN, short* wsN) {
        __syncthreads();
        if (d0 + 64 < Dc) swrite(asN, wsN);
        if (d0 + 128 < Dc) gload(d0 + 128);
        #pragma unroll
        for (int kc = 0; kc < 64; kc += 32) {
            bf16x8 afr[2], bfr[4];
            #pragma unroll
            for (int ms = 0; ms < 2; ++ms)
                afr[ms] = *(const bf16x8*)&asC[(w * 32 + ms * 16 + l15) * 72 + kc + g * 8];
            #pragma unroll
            for (int nb = 0; nb < 4; ++nb)
                bfr[nb] = *(const bf16x8*)&wsC[(nb * 16 + l15) * 72 + kc + g * 8];
            #pragma unroll
            for (int ms = 0; ms < 2; ++ms)
                #pragma unroll
                for (int nb = 0; nb < 4; ++nb)
                    acc[ms][nb] = MFMA16(afr[ms], bfr[nb], acc[ms][nb]);
        }
    };

    for (int d0 = 0; d0 < Dc; d0 += 128) {
        half(d0,      asA, wsA, asB, wsB);
        half(d0 + 64, asB, wsB, asA, wsA);
    }

    #pragma unroll
    for (int ms = 0; ms < 2; ++ms)
        #pragma unroll
        for (int nb = 0; nb < 4; ++nb)
            #pragma unroll
            for (int r = 0; r < 4; ++r)
                out[(size_t)(m0 + w * 32 + ms * 16 + g * 4 + r) * 1024
                    + n0 + nb * 16 + l15] = acc[ms][nb][r];
}

// ---------------------------------------------------------------------------
extern "C" void kernel_launch(void* const* d_in, const int* in_sizes, int n_in,
                              void* d_out, int out_size, void* d_ws, size_t ws_size,
                              hipStream_t stream) {
    (void)in_sizes; (void)n_in; (void)out_size; (void)ws_size;
    const float* q  = (const float*)d_in[0];
    const float* k  = (const float*)d_in[1];
    const float* v  = (const float*)d_in[2];
    const float* Wq = (const float*)d_in[3];
    const float* Wk = (const float*)d_in[4];
    const float* Wv = (const float*)d_in[5];
    const float* Wo = (const float*)d_in[6];
    float* out = (float*)d_out;

    // ws (shorts unless noted):
    // Xb[3*4096*1024] (REUSED as O4a|O4b after proj) | Q | K | Vt (4M each)
    // | WqT | WkT | WvT | WoT (1M each) | mrow f32 (64K)  => ~58.8 MiB
    short* Xb  = (short*)d_ws;
    short* O4a = Xb;                  // Xb dead after proj; 2*BHSF <= 3*4096*1024
    short* O4b = Xb + BHSF;
    short* Qw  = Xb  + (size_t)3 * 4096 * Dc;
    short* Kw  = Qw  + BHSF;
    short* Vt  = Kw  + BHSF;
    short* WqT = Vt  + BHSF;
    short* WkT = WqT + Hc * Dc * Fc;
    short* WvT = WkT + Hc * Dc * Fc;
    short* WoT = WvT + Hc * Dc * Fc;
    float* mw  = (float*)(WoT + Dc * Dc);

    xcvt_kernel<<<dim3(1024, 3), 256, 0, stream>>>(q, k, v, Xb);
    tcvt_all_kernel<<<dim3(16, 1, 64), 256, 0, stream>>>(Wq, Wk, Wv, Wo,
                                                         WqT, WkT, WvT, WoT);
    proj_kernel<<<dim3(32, 8, 3), 256, 0, stream>>>(Xb, WqT, WkT, WvT,
                                                    Qw, Kw, Vt);
    stats_kernel<<<dim3(32, 16), 256, 0, stream>>>(Qw, Kw, mw);
    attn_kernel<<<dim3(32, 2, 8), 256, 0, stream>>>(Qw, Kw, Vt, mw, O4a, O4b);
    outgemm_kernel<<<dim3(32, 16), 256, 0, stream>>>(O4a, O4b, WoT, out);
}

// Round 14
// 196.539 us; speedup vs baseline: 1.1427x; 1.1427x over previous
//
#include <hip/hip_runtime.h>
#include <hip/hip_bf16.h>
#include <stdint.h>

// Problem dims (fixed)
#define Bc 2
#define Sc 2048
#define Dc 1024
#define Hc 16
#define Fc 64
constexpr int BHSF = Bc * Hc * Sc * Fc;   // 4,194,304

typedef __attribute__((ext_vector_type(8))) short bf16x8;   // MFMA A/B frag (4 VGPR)
typedef __attribute__((ext_vector_type(4))) float f32x4;    // MFMA C/D frag

#define MFMA16(a, b, c) __builtin_amdgcn_mfma_f32_16x16x32_bf16(a, b, c, 0, 0, 0)
#define EXP2(x) __builtin_amdgcn_exp2f(x)
#define SCALE2 0.18033688f   /* 0.125 * log2(e); Q is PRE-SCALED by this in proj */

__device__ inline short f2bfn(float x) {          // native RNE fp32->bf16
    __hip_bfloat16 h = __float2bfloat16(x);
    return __builtin_bit_cast(short, h);
}
__device__ inline uint32_t cvt2(float lo, float hi) {   // packed bf16 pair
    uint32_t a = (uint16_t)f2bfn(lo);
    uint32_t b = (uint16_t)f2bfn(hi);
    return a | (b << 16);          // compiler fuses to v_cvt_pk_bf16_f32
}
__device__ inline float bf2f(short s) {
    uint32_t u = ((uint32_t)(uint16_t)s) << 16;
    return __builtin_bit_cast(float, u);
}

// async global->LDS, 16B per lane. LDS dest = wave-uniform base + lane*16 (m104);
// global src is per-lane. AS3 pointer = low 32 bits of the flat LDS address.
__device__ inline void dma16(const short* g, short* l) {
    __builtin_amdgcn_global_load_lds(
        (const __attribute__((address_space(1))) void*)g,
        (__attribute__((address_space(3))) void*)(uintptr_t)(uint32_t)(uintptr_t)l,
        16, 0, 0);
}

// ---------------------------------------------------------------------------
// K0a: elementwise fp32 -> bf16 for q,k,v into Xb[3][4096][1024]
// grid (1024, 3), 256 thr, 16 elems/thr.
// ---------------------------------------------------------------------------
__global__ __launch_bounds__(256) void xcvt_kernel(
    const float* __restrict__ a, const float* __restrict__ b,
    const float* __restrict__ c, short* __restrict__ out)
{
    const float* src = (blockIdx.y == 0) ? a : (blockIdx.y == 1) ? b : c;
    const size_t base = (size_t)blockIdx.x * 4096 + threadIdx.x * 16;
    const float* s = src + base;
    short* d = out + (size_t)blockIdx.y * 4096 * 1024 + base;
    f32x4 v0 = ((const f32x4*)s)[0], v1 = ((const f32x4*)s)[1];
    f32x4 v2 = ((const f32x4*)s)[2], v3 = ((const f32x4*)s)[3];
    bf16x8 p0, p1;
    #pragma unroll
    for (int i = 0; i < 4; ++i) {
        p0[i] = f2bfn(v0[i]); p0[4 + i] = f2bfn(v1[i]);
        p1[i] = f2bfn(v2[i]); p1[4 + i] = f2bfn(v3[i]);
    }
    *(bf16x8*)d       = p0;
    *(bf16x8*)(d + 8) = p1;
}

// ---------------------------------------------------------------------------
// K0b: ALL weight transposes+cvt in one kernel.
// z < 48: QKV weights (sel = z>>4, h = z&15): [1024][64] f32 -> [64][1024] bf16
// z >= 48: Wo col-strip n0 = (z-48)*64:       [1024][1024]  -> [1024][1024]
// grid (16, 1, 64), 256 thr.
// ---------------------------------------------------------------------------
__global__ __launch_bounds__(256) void tcvt_all_kernel(
    const float* __restrict__ Wq, const float* __restrict__ Wk,
    const float* __restrict__ Wv, const float* __restrict__ Wo,
    short* __restrict__ WqT, short* __restrict__ WkT,
    short* __restrict__ WvT, short* __restrict__ WoT)
{
    __shared__ short td[64 * 72];
    const int t = threadIdx.x;
    const int sr = t >> 2, sc = (t & 3) * 16;
    const int zp = blockIdx.z;
    const int m0 = blockIdx.x * 64;

    const float* in; short* out; int N, n0;
    if (zp < 48) {
        const int sel = zp >> 4, h = zp & 15;
        in  = ((sel == 0) ? Wq : (sel == 1) ? Wk : Wv) + (size_t)h * Dc * Fc;
        out = ((sel == 0) ? WqT : (sel == 1) ? WkT : WvT) + (size_t)h * Fc * Dc;
        N = Fc; n0 = 0;
    } else {
        in = Wo; out = WoT; N = Dc; n0 = (zp - 48) * 64;
    }

    const float* src = in + (size_t)(m0 + sr) * N + n0 + sc;
    #pragma unroll
    for (int i = 0; i < 16; i += 4) {
        f32x4 a = *(const f32x4*)(src + i);
        td[sr * 72 + sc + i + 0] = f2bfn(a[0]);
        td[sr * 72 + sc + i + 1] = f2bfn(a[1]);
        td[sr * 72 + sc + i + 2] = f2bfn(a[2]);
        td[sr * 72 + sc + i + 3] = f2bfn(a[3]);
    }
    __syncthreads();
    alignas(16) short vals[16];
    #pragma unroll
    for (int i = 0; i < 16; ++i) vals[i] = td[(sc + i) * 72 + sr];
    short* dst = out + (size_t)(n0 + sr) * Dc + m0 + sc;
    *(bf16x8*)dst       = *(const bf16x8*)&vals[0];
    *(bf16x8*)(dst + 8) = *(const bf16x8*)&vals[8];
}

// ---------------------------------------------------------------------------
// K1: QKV projection from bf16 Xb, m97-style staging via global_load_lds,
// LINEAR [128][32] LDS tiles, double-buffered, BK=32. [r12 verbatim]
// grid (32 mt, 8 hp, 3 z), mt fastest (XCD-share of x slab).
// ---------------------------------------------------------------------------
__global__ __launch_bounds__(256) void proj_kernel(
    const short* __restrict__ Xb,
    const short* __restrict__ WqT, const short* __restrict__ WkT,
    const short* __restrict__ WvT,
    short* __restrict__ Qo, short* __restrict__ Ko, short* __restrict__ VtO)
{
    const int mt = blockIdx.x, hp = blockIdx.y, z = blockIdx.z;
    const short* X  = Xb + (size_t)z * 4096 * Dc;
    const short* Wt = ((z == 0) ? WqT : (z == 1) ? WkT : WvT) + (size_t)hp * 128 * Dc;
    const int m0 = mt * 128;

    // per buf: [0,4096) = x[128][32], [4096,8192) = w[128][32]  (32 KB total)
    __shared__ short sm[2][8192];

    const int t = threadIdx.x, lane = t & 63, w = t >> 6;
    const int wm = w >> 1, wn = w & 1;
    const int l15 = lane & 15, g = lane >> 4;
    const int lr = lane >> 2, lc = (lane & 3) * 8;   // DMA lane map (16 rows/instr)

    auto issue = [&](int buf, int d0) {
        #pragma unroll
        for (int i = 0; i < 2; ++i) {
            const int rr = (w * 2 + i) * 16 + lr;
            dma16(&X [(size_t)(m0 + rr) * Dc + d0 + lc],
                  &sm[buf][(w * 2 + i) * 512]);
            dma16(&Wt[(size_t)rr        * Dc + d0 + lc],
                  &sm[buf][4096 + (w * 2 + i) * 512]);
        }
    };

    f32x4 acc[4][4];
    #pragma unroll
    for (int i = 0; i < 4; ++i)
        #pragma unroll
        for (int j = 0; j < 4; ++j) acc[i][j] = (f32x4){0.f, 0.f, 0.f, 0.f};

    issue(0, 0);

    for (int d0 = 0; d0 < Dc; d0 += 32) {
        const int cur = (d0 >> 5) & 1;
        __syncthreads();                      // buf[cur] DMA complete
        if (d0 + 32 < Dc) issue(cur ^ 1, d0 + 32);   // in flight across compute
        const short* xb = &sm[cur][0];
        const short* wb = &sm[cur][4096];
        bf16x8 afr[4], bfr[4];
        #pragma unroll
        for (int ms = 0; ms < 4; ++ms)
            afr[ms] = *(const bf16x8*)&xb[(wm * 64 + ms * 16 + l15) * 32 + g * 8];
        #pragma unroll
        for (int fb = 0; fb < 4; ++fb)
            bfr[fb] = *(const bf16x8*)&wb[(wn * 64 + fb * 16 + l15) * 32 + g * 8];
        #pragma unroll
        for (int ms = 0; ms < 4; ++ms)
            #pragma unroll
            for (int fb = 0; fb < 4; ++fb)
                acc[ms][fb] = MFMA16(afr[ms], bfr[fb], acc[ms][fb]);
    }

    // Epilogue: 2 passes through an 18KB bounce overlaid on sm (flat view).
    short* ob = &sm[0][0];                    // [128][72]
    const float oscale = (z == 0) ? SCALE2 : 1.0f;
    const int b = m0 >> 11, s0 = m0 & 2047;
    #pragma unroll
    for (int p = 0; p < 2; ++p) {
        __syncthreads();                      // ob free
        if (wn == p) {
            #pragma unroll
            for (int ms = 0; ms < 4; ++ms)
                #pragma unroll
                for (int fb = 0; fb < 4; ++fb)
                    #pragma unroll
                    for (int r = 0; r < 4; ++r)
                        ob[(wm * 64 + ms * 16 + g * 4 + r) * 72 + fb * 16 + l15] =
                            f2bfn(acc[ms][fb][r] * oscale);
        }
        __syncthreads();
        const int h = hp * 2 + p;
        if (z < 2) {
            const int row = t >> 1, c0 = (t & 1) * 32;
            short* outp = ((z == 0) ? Qo : Ko)
                        + ((size_t)(b * Hc + h) * Sc + s0 + row) * Fc + c0;
            #pragma unroll
            for (int j = 0; j < 32; j += 8)
                *(bf16x8*)&outp[j] = *(const bf16x8*)&ob[row * 72 + c0 + j];
        } else {
            const int f = t >> 2, cg = (t & 3) * 32;
            short* o = VtO + ((size_t)(b * Hc + h) * Fc + f) * Sc + s0 + cg;
            alignas(16) short vals[32];
            #pragma unroll
            for (int j = 0; j < 32; ++j) vals[j] = ob[(cg + j) * 72 + f];
            #pragma unroll
            for (int j = 0; j < 32; j += 8)
                *(bf16x8*)(o + j) = *(const bf16x8*)&vals[j];
        }
    }
}

// ---------------------------------------------------------------------------
// K2: softmax denom [r12 verbatim]. NO max tracking; l = sum exp2(s');
// writes m' = log2(l). Single-barrier dbuf K staging. bh fastest (XCD).
// grid (32 bh, 16 qt), 256 thr.
// ---------------------------------------------------------------------------
__global__ __launch_bounds__(256) void stats_kernel(
    const short* __restrict__ Qg, const short* __restrict__ Kg,
    float* __restrict__ mrow)
{
    const int bh = blockIdx.x;
    const int q0 = blockIdx.y * 128;
    const short* Qb = Qg + (size_t)bh * Sc * Fc;
    const short* Kb = Kg + (size_t)bh * Sc * Fc;

    __shared__ short ksA[64 * 72], ksB[64 * 72];

    const int t = threadIdx.x, lane = t & 63, w = t >> 6;
    const int l15 = lane & 15, g = lane >> 4;
    const int sr4 = t >> 2, sc4 = (t & 3) * 16;

    bf16x8 qf[2][2];
    #pragma unroll
    for (int qs2 = 0; qs2 < 2; ++qs2)
        #pragma unroll
        for (int kc2 = 0; kc2 < 2; ++kc2)
            qf[qs2][kc2] = *(const bf16x8*)
                &Qb[(size_t)(q0 + w * 32 + qs2 * 16 + l15) * Fc + kc2 * 32 + g * 8];

    bf16x8 kr0, kr1;
    auto gload = [&](int kt) {
        const short* s = &Kb[(size_t)(kt + sr4) * Fc + sc4];
        kr0 = *(const bf16x8*)s;
        kr1 = *(const bf16x8*)(s + 8);
    };
    auto swrite = [&](short* d) {
        *(bf16x8*)&d[sr4 * 72 + sc4]     = kr0;
        *(bf16x8*)&d[sr4 * 72 + sc4 + 8] = kr1;
    };

    f32x4 ls[2];
    ls[0] = (f32x4){0.f, 0.f, 0.f, 0.f};
    ls[1] = (f32x4){0.f, 0.f, 0.f, 0.f};

    gload(0); swrite(ksA); gload(64);

    auto half = [&](int kt, const short* cur, short* nxt) {
        __syncthreads();
        if (kt + 64 < Sc) swrite(nxt);
        if (kt + 128 < Sc) gload(kt + 128);
        #pragma unroll
        for (int kf = 0; kf < 4; ++kf) {
            bf16x8 a0 = *(const bf16x8*)&cur[(kf * 16 + l15) * 72 + 0  + g * 8];
            bf16x8 a1 = *(const bf16x8*)&cur[(kf * 16 + l15) * 72 + 32 + g * 8];
            #pragma unroll
            for (int qs2 = 0; qs2 < 2; ++qs2) {
                f32x4 acc = (f32x4){0.f, 0.f, 0.f, 0.f};
                acc = MFMA16(a0, qf[qs2][0], acc);
                acc = MFMA16(a1, qf[qs2][1], acc);   // same d-split order as attn
                #pragma unroll
                for (int r = 0; r < 4; ++r) ls[qs2][r] += EXP2(acc[r]);
            }
        }
    };

    for (int kt = 0; kt < Sc; kt += 128) {
        half(kt,      ksA, ksB);
        half(kt + 64, ksB, ksA);
    }

    #pragma unroll
    for (int qs2 = 0; qs2 < 2; ++qs2) {
        float l = (ls[qs2][0] + ls[qs2][1]) + (ls[qs2][2] + ls[qs2][3]);
        l += __shfl_xor(l, 16, 64);
        l += __shfl_xor(l, 32, 64);
        if (lane < 16)
            mrow[bh * Sc + q0 + w * 32 + qs2 * 16 + l15] = __log2f(l);
    }
}

// ---------------------------------------------------------------------------
// K3: attention — r13 structure (direct-global Q/V/m', private P^T in LDS,
// ZERO barriers in main loop; addressing refcheck-verified in r13) WITHOUT
// the chunk double-buffers that spilled (r13: 82 MB scratch writes).
// Loads issued once at chunk top; L2 latency hidden by TLP (2 waves/SIMD)
// + the ~460 cyc of MFMA/VALU per chunk. VGPR budget ~180, no spill.
// LDS instrs/wave-chunk: 44 (r12) -> 24.
// grid (32 bh, 2 qh, 8 kt), 256 thr / 4 waves.
// ---------------------------------------------------------------------------
__global__ __launch_bounds__(256) void attn_kernel(
    const short* __restrict__ Qg, const short* __restrict__ Kg,
    const short* __restrict__ VtG, const float* __restrict__ mrow,
    short* __restrict__ O4a, short* __restrict__ O4b)
{
    const int bh = blockIdx.x;
    const int qh = blockIdx.y;
    const int k0 = blockIdx.z * 256;
    const int qbeg = qh * 1024, qend = qbeg + 1024;
    const short* Qb = Qg  + (size_t)bh * Sc * Fc;
    const short* Kb = Kg  + (size_t)bh * Sc * Fc;
    const short* Vb = VtG + (size_t)bh * Fc * Sc;   // [64 f][2048 s]
    const float* mb = mrow + (size_t)bh * Sc;

    __shared__ short pl[4][64 * 72];   // P^T, per-wave PRIVATE; out-bounce at end

    const int t = threadIdx.x, lane = t & 63, w = t >> 6;   // w 0..3
    const int l15 = lane & 15, g = lane >> 4;
    short* plw = &pl[w][0];

    // resident K B-frags: wave w owns k-cols k0 + w*64 + ks*16 + l15
    bf16x8 kf[4][2];
    #pragma unroll
    for (int ks = 0; ks < 4; ++ks)
        #pragma unroll
        for (int kc = 0; kc < 2; ++kc)
            kf[ks][kc] = *(const bf16x8*)
                &Kb[(size_t)(k0 + w * 64 + ks * 16 + l15) * Fc + kc * 32 + g * 8];

    // per-lane global fragment bases (16 rows x 64B fully-used lines)
    const short* qbase = Qb + (size_t)l15 * Fc + g * 8;
    const short* vbase = Vb + (size_t)l15 * Sc + g * 8;

    f32x4 oacc[4][4];
    #pragma unroll
    for (int i = 0; i < 4; ++i)
        #pragma unroll
        for (int j = 0; j < 4; ++j) oacc[i][j] = (f32x4){0.f, 0.f, 0.f, 0.f};

    for (int q0 = qbeg; q0 < qend; q0 += 64) {
        // load this chunk's Q-frags, V-frags, m' (L2-resident per XCD, r12)
        bf16x8 qa[4][2];
        bf16x8 vf[2][4];
        f32x4  mq[4];
        #pragma unroll
        for (int qf = 0; qf < 4; ++qf) {
            const short* s = qbase + (size_t)(q0 + qf * 16) * Fc;
            qa[qf][0] = *(const bf16x8*)s;
            qa[qf][1] = *(const bf16x8*)(s + 32);
            mq[qf] = *(const f32x4*)&mb[q0 + qf * 16 + g * 4];
        }
        #pragma unroll
        for (int c = 0; c < 2; ++c)
            #pragma unroll
            for (int fb = 0; fb < 4; ++fb)
                vf[c][fb] = *(const bf16x8*)
                    (vbase + (size_t)fb * 16 * Sc + q0 + c * 32);

        // phase A: S = mfma(Q,K); C row=q (qf*16+g*4+r), col=k (w*64+ks*16+l15)
        #pragma unroll
        for (int qf = 0; qf < 4; ++qf) {
            #pragma unroll
            for (int ks = 0; ks < 4; ++ks) {
                f32x4 acc = (f32x4){0.f, 0.f, 0.f, 0.f};
                acc = MFMA16(qa[qf][0], kf[ks][0], acc);
                acc = MFMA16(qa[qf][1], kf[ks][1], acc);
                uint2 pv;
                pv.x = cvt2(EXP2(acc[0] - mq[qf][0]), EXP2(acc[1] - mq[qf][1]));
                pv.y = cvt2(EXP2(acc[2] - mq[qf][2]), EXP2(acc[3] - mq[qf][3]));
                *(uint2*)&plw[(ks * 16 + l15) * 72 + qf * 16 + g * 4] = pv;
            }
        }
        // NO barrier: pl rows are private to this wave (wave-internal lgkmcnt).

        // phase B: PV.  A = own P^T rows (LDS), B = Vt frags (registers).
        #pragma unroll
        for (int qc = 0; qc < 2; ++qc) {
            bf16x8 pa[4];
            #pragma unroll
            for (int ks = 0; ks < 4; ++ks)
                pa[ks] = *(const bf16x8*)&plw[(ks * 16 + l15) * 72 + qc * 32 + g * 8];
            #pragma unroll
            for (int ks = 0; ks < 4; ++ks)
                #pragma unroll
                for (int fb = 0; fb < 4; ++fb)
                    oacc[ks][fb] = MFMA16(pa[ks], vf[qc][fb], oacc[ks][fb]);
        }
    }

    // epilogue: bounce via pl (flat 256 rows x 64) for coalesced bf16 stores
    __syncthreads();
    #pragma unroll
    for (int ks = 0; ks < 4; ++ks)
        #pragma unroll
        for (int fb = 0; fb < 4; ++fb)
            #pragma unroll
            for (int r = 0; r < 4; ++r)
                plw[(ks * 16 + g * 4 + r) * 72 + fb * 16 + l15] =
                    f2bfn(oacc[ks][fb][r]);
    __syncthreads();
    {
        const short* plf = &pl[0][0];
        short* O = qh ? O4b : O4a;
        short* o = O + ((size_t)bh * Sc + k0 + t) * Fc;
        #pragma unroll
        for (int j = 0; j < 64; j += 8)
            *(bf16x8*)&o[j] = *(const bf16x8*)&plf[t * 72 + j];
    }
}

// ---------------------------------------------------------------------------
// K4: out(fp32) = (O4a + O4b) @ Wo [r12 verbatim]. NT, dbuf, partial-sum in
// A-staging. m-tile 128 (msub=2). grid (32, 16), 256 thr.
// ---------------------------------------------------------------------------
__global__ __launch_bounds__(256) void outgemm_kernel(
    const short* __restrict__ Aa, const short* __restrict__ Ab,
    const short* __restrict__ WoT, float* __restrict__ out)
{
    const int m0 = blockIdx.x * 128, n0 = blockIdx.y * 64;

    __shared__ short asA[128 * 72], asB[128 * 72];
    __shared__ short wsA[64 * 72],  wsB[64 * 72];

    const int t = threadIdx.x, lane = t & 63, w = t >> 6;
    const int l15 = lane & 15, g = lane >> 4;
    const int ar = t >> 1, ac = (t & 1) * 32;
    const int wr = t >> 2, wc = (t & 3) * 16;

    bf16x8 ag0[4], ag1[4], wg[2];
    auto gload = [&](int d0) {
        const short* s0 = &Aa[(size_t)(m0 + ar) * Dc + d0 + ac];
        const short* s1 = &Ab[(size_t)(m0 + ar) * Dc + d0 + ac];
        #pragma unroll
        for (int j = 0; j < 4; ++j) { ag0[j] = *(const bf16x8*)(s0 + 8 * j);
                                      ag1[j] = *(const bf16x8*)(s1 + 8 * j); }
        const short* ww = &WoT[(size_t)(n0 + wr) * Dc + d0 + wc];
        wg[0] = *(const bf16x8*)ww;
        wg[1] = *(const bf16x8*)(ww + 8);
    };
    auto swrite = [&](short* asD, short* wsD) {
        #pragma unroll
        for (int j = 0; j < 4; ++j) {
            bf16x8 r;
            #pragma unroll
            for (int i = 0; i < 8; ++i)
                r[i] = f2bfn(bf2f(ag0[j][i]) + bf2f(ag1[j][i]));
            *(bf16x8*)&asD[ar * 72 + ac + 8 * j] = r;
        }
        *(bf16x8*)&wsD[wr * 72 + wc]     = wg[0];
        *(bf16x8*)&wsD[wr * 72 + wc + 8] = wg[1];
    };

    f32x4 acc[2][4];
    #pragma unroll
    for (int i = 0; i < 2; ++i)
        #pragma unroll
        for (int j = 0; j < 4; ++j) acc[i][j] = (f32x4){0.f, 0.f, 0.f, 0.f};

    gload(0); swrite(asA, wsA); gload(64);

    auto half = [&](int d0, const short* asC, const short* wsC,
                    short* asN, short* wsN) {
        __syncthreads();
        if (d0 + 64 < Dc) swrite(asN, wsN);
        if (d0 + 128 < Dc) gload(d0 + 128);
        #pragma unroll
        for (int kc = 0; kc < 64; kc += 32) {
            bf16x8 afr[2], bfr[4];
            #pragma unroll
            for (int ms = 0; ms < 2; ++ms)
                afr[ms] = *(const bf16x8*)&asC[(w * 32 + ms * 16 + l15) * 72 + kc + g * 8];
            #pragma unroll
            for (int nb = 0; nb < 4; ++nb)
                bfr[nb] = *(const bf16x8*)&wsC[(nb * 16 + l15) * 72 + kc + g * 8];
            #pragma unroll
            for (int ms = 0; ms < 2; ++ms)
                #pragma unroll
                for (int nb = 0; nb < 4; ++nb)
                    acc[ms][nb] = MFMA16(afr[ms], bfr[nb], acc[ms][nb]);
        }
    };

    for (int d0 = 0; d0 < Dc; d0 += 128) {
        half(d0,      asA, wsA, asB, wsB);
        half(d0 + 64, asB, wsB, asA, wsA);
    }

    #pragma unroll
    for (int ms = 0; ms < 2; ++ms)
        #pragma unroll
        for (int nb = 0; nb < 4; ++nb)
            #pragma unroll
            for (int r = 0; r < 4; ++r)
                out[(size_t)(m0 + w * 32 + ms * 16 + g * 4 + r) * 1024
                    + n0 + nb * 16 + l15] = acc[ms][nb][r];
}

// ---------------------------------------------------------------------------
extern "C" void kernel_launch(void* const* d_in, const int* in_sizes, int n_in,
                              void* d_out, int out_size, void* d_ws, size_t ws_size,
                              hipStream_t stream) {
    (void)in_sizes; (void)n_in; (void)out_size; (void)ws_size;
    const float* q  = (const float*)d_in[0];
    const float* k  = (const float*)d_in[1];
    const float* v  = (const float*)d_in[2];
    const float* Wq = (const float*)d_in[3];
    const float* Wk = (const float*)d_in[4];
    const float* Wv = (const float*)d_in[5];
    const float* Wo = (const float*)d_in[6];
    float* out = (float*)d_out;

    // ws (shorts unless noted):
    // Xb[3*4096*1024] (REUSED as O4a|O4b after proj) | Q | K | Vt (4M each)
    // | WqT | WkT | WvT | WoT (1M each) | mrow f32 (64K)  => ~58.8 MiB
    short* Xb  = (short*)d_ws;
    short* O4a = Xb;                  // Xb dead after proj; 2*BHSF <= 3*4096*1024
    short* O4b = Xb + BHSF;
    short* Qw  = Xb  + (size_t)3 * 4096 * Dc;
    short* Kw  = Qw  + BHSF;
    short* Vt  = Kw  + BHSF;
    short* WqT = Vt  + BHSF;
    short* WkT = WqT + Hc * Dc * Fc;
    short* WvT = WkT + Hc * Dc * Fc;
    short* WoT = WvT + Hc * Dc * Fc;
    float* mw  = (float*)(WoT + Dc * Dc);

    xcvt_kernel<<<dim3(1024, 3), 256, 0, stream>>>(q, k, v, Xb);
    tcvt_all_kernel<<<dim3(16, 1, 64), 256, 0, stream>>>(Wq, Wk, Wv, Wo,
                                                         WqT, WkT, WvT, WoT);
    proj_kernel<<<dim3(32, 8, 3), 256, 0, stream>>>(Xb, WqT, WkT, WvT,
                                                    Qw, Kw, Vt);
    stats_kernel<<<dim3(32, 16), 256, 0, stream>>>(Qw, Kw, mw);
    attn_kernel<<<dim3(32, 2, 8), 256, 0, stream>>>(Qw, Kw, Vt, mw, O4a, O4b);
    outgemm_kernel<<<dim3(32, 16), 256, 0, stream>>>(O4a, O4b, WoT, out);
}

// Round 15
// 156.994 us; speedup vs baseline: 1.4305x; 1.2519x over previous
//
#include <hip/hip_runtime.h>
#include <hip/hip_bf16.h>
#include <stdint.h>

// Problem dims (fixed)
#define Bc 2
#define Sc 2048
#define Dc 1024
#define Hc 16
#define Fc 64
constexpr int BHSF = Bc * Hc * Sc * Fc;   // 4,194,304

typedef __attribute__((ext_vector_type(8))) short bf16x8;   // MFMA A/B frag (4 VGPR)
typedef __attribute__((ext_vector_type(4))) float f32x4;    // MFMA C/D frag

#define MFMA16(a, b, c) __builtin_amdgcn_mfma_f32_16x16x32_bf16(a, b, c, 0, 0, 0)
#define EXP2(x) __builtin_amdgcn_exp2f(x)
#define SCALE2 0.18033688f   /* 0.125 * log2(e); Q is PRE-SCALED by this in proj */

__device__ inline short f2bfn(float x) {          // native RNE fp32->bf16
    __hip_bfloat16 h = __float2bfloat16(x);
    return __builtin_bit_cast(short, h);
}
__device__ inline uint32_t cvt2(float lo, float hi) {   // packed bf16 pair
    uint32_t a = (uint16_t)f2bfn(lo);
    uint32_t b = (uint16_t)f2bfn(hi);
    return a | (b << 16);          // compiler fuses to v_cvt_pk_bf16_f32
}
__device__ inline float bf2f(short s) {
    uint32_t u = ((uint32_t)(uint16_t)s) << 16;
    return __builtin_bit_cast(float, u);
}

// ---------------------------------------------------------------------------
// K0: ALL weight transposes+cvt in one kernel. [r12 verbatim]
// z < 48: QKV weights (sel = z>>4, h = z&15): [1024][64] f32 -> [64][1024] bf16
// z >= 48: Wo col-strip n0 = (z-48)*64:       [1024][1024]  -> [1024][1024]
// grid (16, 1, 64), 256 thr.
// ---------------------------------------------------------------------------
__global__ __launch_bounds__(256) void tcvt_all_kernel(
    const float* __restrict__ Wq, const float* __restrict__ Wk,
    const float* __restrict__ Wv, const float* __restrict__ Wo,
    short* __restrict__ WqT, short* __restrict__ WkT,
    short* __restrict__ WvT, short* __restrict__ WoT)
{
    __shared__ short td[64 * 72];
    const int t = threadIdx.x;
    const int sr = t >> 2, sc = (t & 3) * 16;
    const int zp = blockIdx.z;
    const int m0 = blockIdx.x * 64;

    const float* in; short* out; int N, n0;
    if (zp < 48) {
        const int sel = zp >> 4, h = zp & 15;
        in  = ((sel == 0) ? Wq : (sel == 1) ? Wk : Wv) + (size_t)h * Dc * Fc;
        out = ((sel == 0) ? WqT : (sel == 1) ? WkT : WvT) + (size_t)h * Fc * Dc;
        N = Fc; n0 = 0;
    } else {
        in = Wo; out = WoT; N = Dc; n0 = (zp - 48) * 64;
    }

    const float* src = in + (size_t)(m0 + sr) * N + n0 + sc;
    #pragma unroll
    for (int i = 0; i < 16; i += 4) {
        f32x4 a = *(const f32x4*)(src + i);
        td[sr * 72 + sc + i + 0] = f2bfn(a[0]);
        td[sr * 72 + sc + i + 1] = f2bfn(a[1]);
        td[sr * 72 + sc + i + 2] = f2bfn(a[2]);
        td[sr * 72 + sc + i + 3] = f2bfn(a[3]);
    }
    __syncthreads();
    alignas(16) short vals[16];
    #pragma unroll
    for (int i = 0; i < 16; ++i) vals[i] = td[(sc + i) * 72 + sr];
    short* dst = out + (size_t)(n0 + sr) * Dc + m0 + sc;
    *(bf16x8*)dst       = *(const bf16x8*)&vals[0];
    *(bf16x8*)(dst + 8) = *(const bf16x8*)&vals[8];
}

// ---------------------------------------------------------------------------
// K1: QKV projection DIRECTLY from fp32 x (cvt fused in staging). [r9 verbatim
// — best measured proj path: r11/r12's dma-proj+xcvt cost ~+8.5us net vs this]
// Tile 128m x 128f (h-PAIR), 4 waves 2x2, wave 64x64 (4x4 acc). BK=32, dbuf.
// grid (32 mt, 8 hp, 3 z), mt FASTEST: the 8 hp-blocks sharing an x slab have
// IDs 32 apart == 0 mod 8 -> same XCD -> slab fetched ~once. [r7 fix]
// z=0 Q rows (PRE-SCALED by SCALE2), z=1 K rows, z=2 V transposed [b,h,f,s].
// ---------------------------------------------------------------------------
__global__ __launch_bounds__(256) void proj_kernel(
    const float* __restrict__ xq, const float* __restrict__ xk,
    const float* __restrict__ xv,
    const short* __restrict__ WqT, const short* __restrict__ WkT,
    const short* __restrict__ WvT,
    short* __restrict__ Qo, short* __restrict__ Ko, short* __restrict__ VtO)
{
    const int mt = blockIdx.x, hp = blockIdx.y, z = blockIdx.z;
    const float* x  = (z == 0) ? xq : (z == 1) ? xk : xv;
    const short* Wt = ((z == 0) ? WqT : (z == 1) ? WkT : WvT) + (size_t)hp * 128 * Dc;
    const int m0 = mt * 128;

    __shared__ short xs[2][128 * 40];   // A tiles [128 m][32 d], pad 40
    __shared__ short ws[2][128 * 40];   // B tiles [128 f][32 d]

    const int t = threadIdx.x, lane = t & 63, w = t >> 6;
    const int wm = w >> 1, wn = w & 1;
    const int l15 = lane & 15, g = lane >> 4;
    const int str = t >> 1, stc = (t & 1) * 16;

    f32x4 xg[4]; bf16x8 wg[2];
    auto gload = [&](int d0) {
        const float* s = &x[(size_t)(m0 + str) * Dc + d0 + stc];
        #pragma unroll
        for (int j = 0; j < 4; ++j) xg[j] = ((const f32x4*)s)[j];
        const short* ww = &Wt[(size_t)str * Dc + d0 + stc];
        wg[0] = *(const bf16x8*)ww;
        wg[1] = *(const bf16x8*)(ww + 8);
    };
    auto swrite = [&](int buf) {
        bf16x8 p0, p1;
        #pragma unroll
        for (int i = 0; i < 4; ++i) {
            p0[i] = f2bfn(xg[0][i]); p0[4 + i] = f2bfn(xg[1][i]);
            p1[i] = f2bfn(xg[2][i]); p1[4 + i] = f2bfn(xg[3][i]);
        }
        *(bf16x8*)&xs[buf][str * 40 + stc]     = p0;
        *(bf16x8*)&xs[buf][str * 40 + stc + 8] = p1;
        *(bf16x8*)&ws[buf][str * 40 + stc]     = wg[0];
        *(bf16x8*)&ws[buf][str * 40 + stc + 8] = wg[1];
    };

    f32x4 acc[4][4];
    #pragma unroll
    for (int i = 0; i < 4; ++i)
        #pragma unroll
        for (int j = 0; j < 4; ++j) acc[i][j] = (f32x4){0.f, 0.f, 0.f, 0.f};

    gload(0); swrite(0); gload(32);

    auto step = [&](int d0, int cur) {
        __syncthreads();
        if (d0 + 32 < Dc) swrite(cur ^ 1);
        if (d0 + 64 < Dc) gload(d0 + 64);
        bf16x8 afr[4], bfr[4];
        #pragma unroll
        for (int ms = 0; ms < 4; ++ms)
            afr[ms] = *(const bf16x8*)&xs[cur][(wm * 64 + ms * 16 + l15) * 40 + g * 8];
        #pragma unroll
        for (int fb = 0; fb < 4; ++fb)
            bfr[fb] = *(const bf16x8*)&ws[cur][(wn * 64 + fb * 16 + l15) * 40 + g * 8];
        #pragma unroll
        for (int ms = 0; ms < 4; ++ms)
            #pragma unroll
            for (int fb = 0; fb < 4; ++fb)
                acc[ms][fb] = MFMA16(afr[ms], bfr[fb], acc[ms][fb]);
    };

    for (int d0 = 0; d0 < Dc; d0 += 64) {
        step(d0, 0);
        step(d0 + 32, 1);
    }

    // epilogue: bounce into xs (wn=0 half, viewed [128][80]) / ws (wn=1 half)
    const float oscale = (z == 0) ? SCALE2 : 1.0f;
    __syncthreads();
    {
        short* bb = wn ? &ws[0][0] : &xs[0][0];
        #pragma unroll
        for (int ms = 0; ms < 4; ++ms)
            #pragma unroll
            for (int fb = 0; fb < 4; ++fb)
                #pragma unroll
                for (int r = 0; r < 4; ++r)
                    bb[(wm * 64 + ms * 16 + g * 4 + r) * 80 + fb * 16 + l15] =
                        f2bfn(acc[ms][fb][r] * oscale);
    }
    __syncthreads();

    const int b = m0 >> 11, s0 = m0 & 2047;
    if (z < 2) {
        const int row = t & 127, half = t >> 7;
        const short* src = (half ? &ws[0][0] : &xs[0][0]) + row * 80;
        short* outp = ((z == 0) ? Qo : Ko)
                    + ((size_t)(b * Hc + hp * 2 + half) * Sc + s0 + row) * Fc;
        #pragma unroll
        for (int j = 0; j < 64; j += 8)
            *(bf16x8*)&outp[j] = *(const bf16x8*)&src[j];
    } else {
        // Vt[b,h,f,s]: gather columns (transpose) from the bounce buffers
        const int fhr = t & 127, half = fhr >> 6, f = fhr & 63;
        const int colg = t >> 7;
        const short* src = half ? &ws[0][0] : &xs[0][0];
        short* o = VtO + ((size_t)(b * Hc + hp * 2 + half) * Fc + f) * Sc
                       + s0 + colg * 64;
        alignas(16) short vals[64];
        #pragma unroll
        for (int j = 0; j < 64; ++j) vals[j] = src[(colg * 64 + j) * 80 + f];
        #pragma unroll
        for (int j = 0; j < 64; j += 8)
            *(bf16x8*)(o + j) = *(const bf16x8*)&vals[j];
    }
}

// ---------------------------------------------------------------------------
// K2: softmax denom [r12 verbatim]. NO max tracking; l = sum exp2(s');
// writes m' = log2(l). Single-barrier dbuf K staging. bh fastest (XCD).
// grid (32 bh, 16 qt), 256 thr.
// ---------------------------------------------------------------------------
__global__ __launch_bounds__(256) void stats_kernel(
    const short* __restrict__ Qg, const short* __restrict__ Kg,
    float* __restrict__ mrow)
{
    const int bh = blockIdx.x;
    const int q0 = blockIdx.y * 128;
    const short* Qb = Qg + (size_t)bh * Sc * Fc;
    const short* Kb = Kg + (size_t)bh * Sc * Fc;

    __shared__ short ksA[64 * 72], ksB[64 * 72];

    const int t = threadIdx.x, lane = t & 63, w = t >> 6;
    const int l15 = lane & 15, g = lane >> 4;
    const int sr4 = t >> 2, sc4 = (t & 3) * 16;

    bf16x8 qf[2][2];
    #pragma unroll
    for (int qs2 = 0; qs2 < 2; ++qs2)
        #pragma unroll
        for (int kc2 = 0; kc2 < 2; ++kc2)
            qf[qs2][kc2] = *(const bf16x8*)
                &Qb[(size_t)(q0 + w * 32 + qs2 * 16 + l15) * Fc + kc2 * 32 + g * 8];

    bf16x8 kr0, kr1;
    auto gload = [&](int kt) {
        const short* s = &Kb[(size_t)(kt + sr4) * Fc + sc4];
        kr0 = *(const bf16x8*)s;
        kr1 = *(const bf16x8*)(s + 8);
    };
    auto swrite = [&](short* d) {
        *(bf16x8*)&d[sr4 * 72 + sc4]     = kr0;
        *(bf16x8*)&d[sr4 * 72 + sc4 + 8] = kr1;
    };

    f32x4 ls[2];
    ls[0] = (f32x4){0.f, 0.f, 0.f, 0.f};
    ls[1] = (f32x4){0.f, 0.f, 0.f, 0.f};

    gload(0); swrite(ksA); gload(64);

    auto half = [&](int kt, const short* cur, short* nxt) {
        __syncthreads();
        if (kt + 64 < Sc) swrite(nxt);
        if (kt + 128 < Sc) gload(kt + 128);
        #pragma unroll
        for (int kf = 0; kf < 4; ++kf) {
            bf16x8 a0 = *(const bf16x8*)&cur[(kf * 16 + l15) * 72 + 0  + g * 8];
            bf16x8 a1 = *(const bf16x8*)&cur[(kf * 16 + l15) * 72 + 32 + g * 8];
            #pragma unroll
            for (int qs2 = 0; qs2 < 2; ++qs2) {
                f32x4 acc = (f32x4){0.f, 0.f, 0.f, 0.f};
                acc = MFMA16(a0, qf[qs2][0], acc);
                acc = MFMA16(a1, qf[qs2][1], acc);   // same d-split order as attn
                #pragma unroll
                for (int r = 0; r < 4; ++r) ls[qs2][r] += EXP2(acc[r]);
            }
        }
    };

    for (int kt = 0; kt < Sc; kt += 128) {
        half(kt,      ksA, ksB);
        half(kt + 64, ksB, ksA);
    }

    #pragma unroll
    for (int qs2 = 0; qs2 < 2; ++qs2) {
        float l = (ls[qs2][0] + ls[qs2][1]) + (ls[qs2][2] + ls[qs2][3]);
        l += __shfl_xor(l, 16, 64);
        l += __shfl_xor(l, 32, 64);
        if (lane < 16)
            mrow[bh * Sc + q0 + w * 32 + qs2 * 16 + l15] = __log2f(l);
    }
}

// ---------------------------------------------------------------------------
// K3: attention [r12 verbatim — best measured: 58.4us, FETCH 12.5MB].
// LDS-staged Q/Vt (reg-staged dbuf), resident kf[4][2], private-P^T (no
// barrier between P-write and PV), XCD-ordered grid (bh fastest).
// grid (32 bh, 2 qh, 8 kt), 256 thr / 4 waves.
// ---------------------------------------------------------------------------
__global__ __launch_bounds__(256) void attn_kernel(
    const short* __restrict__ Qg, const short* __restrict__ Kg,
    const short* __restrict__ VtG, const float* __restrict__ mrow,
    short* __restrict__ O4a, short* __restrict__ O4b)
{
    const int bh = blockIdx.x;
    const int qh = blockIdx.y;
    const int k0 = blockIdx.z * 256;
    const int qbeg = qh * 1024, qend = qbeg + 1024;
    const short* Qb = Qg  + (size_t)bh * Sc * Fc;
    const short* Kb = Kg  + (size_t)bh * Sc * Fc;
    const short* Vb = VtG + (size_t)bh * Fc * Sc;   // [64 f][2048 s]
    const float* mb = mrow + (size_t)bh * Sc;

    __shared__ short qs[64 * 72];
    __shared__ short vt[64 * 72];
    __shared__ short pl[256 * 72];   // P^T; per-wave PRIVATE rows; out-bounce at end

    const int t = threadIdx.x, lane = t & 63, w = t >> 6;   // w 0..3
    const int l15 = lane & 15, g = lane >> 4;
    const int sr8 = t >> 2, sc8 = (t & 3) * 16;

    // resident K B-frags: wave w owns k-cols k0 + w*64 + ks*16 + l15
    bf16x8 kf[4][2];
    #pragma unroll
    for (int ks = 0; ks < 4; ++ks)
        #pragma unroll
        for (int kc = 0; kc < 2; ++kc)
            kf[ks][kc] = *(const bf16x8*)
                &Kb[(size_t)(k0 + w * 64 + ks * 16 + l15) * Fc + kc * 32 + g * 8];

    f32x4 oacc[4][4];
    #pragma unroll
    for (int i = 0; i < 4; ++i)
        #pragma unroll
        for (int j = 0; j < 4; ++j) oacc[i][j] = (f32x4){0.f, 0.f, 0.f, 0.f};

    bf16x8 qr0, qr1, vr0, vr1;
    auto gload = [&](int qn) {
        const short* s = &Qb[(size_t)(qn + sr8) * Fc + sc8];
        qr0 = *(const bf16x8*)s;
        qr1 = *(const bf16x8*)(s + 8);
        const short* v = &Vb[(size_t)sr8 * Sc + qn + sc8];
        vr0 = *(const bf16x8*)v;
        vr1 = *(const bf16x8*)(v + 8);
    };

    gload(qbeg);

    for (int q0 = qbeg; q0 < qend; q0 += 64) {
        __syncthreads();                          // (1) prev PV done with qs/vt
        *(bf16x8*)&qs[sr8 * 72 + sc8]     = qr0;
        *(bf16x8*)&qs[sr8 * 72 + sc8 + 8] = qr1;
        *(bf16x8*)&vt[sr8 * 72 + sc8]     = vr0;
        *(bf16x8*)&vt[sr8 * 72 + sc8 + 8] = vr1;
        if (q0 + 64 < qend) gload(q0 + 64);
        f32x4 mq[4];
        #pragma unroll
        for (int qf = 0; qf < 4; ++qf)
            mq[qf] = *(const f32x4*)&mb[q0 + qf * 16 + g * 4];
        __syncthreads();                          // (2) qs/vt visible

        // phase A: S = mfma(Q,K); C row=q (qf*16+g*4+r), col=k (w*64+ks*16+l15)
        #pragma unroll
        for (int qf = 0; qf < 4; ++qf) {
            bf16x8 qa0 = *(const bf16x8*)&qs[(qf * 16 + l15) * 72 + 0  + g * 8];
            bf16x8 qa1 = *(const bf16x8*)&qs[(qf * 16 + l15) * 72 + 32 + g * 8];
            #pragma unroll
            for (int ks = 0; ks < 4; ++ks) {
                f32x4 acc = (f32x4){0.f, 0.f, 0.f, 0.f};
                acc = MFMA16(qa0, kf[ks][0], acc);
                acc = MFMA16(qa1, kf[ks][1], acc);
                uint2 pv;
                pv.x = cvt2(EXP2(acc[0] - mq[qf][0]), EXP2(acc[1] - mq[qf][1]));
                pv.y = cvt2(EXP2(acc[2] - mq[qf][2]), EXP2(acc[3] - mq[qf][3]));
                *(uint2*)&pl[(w * 64 + ks * 16 + l15) * 72 + qf * 16 + g * 4] = pv;
            }
        }
        // NO barrier: pl rows w*64.. are private to this wave (wave-internal
        // ds_write -> ds_read ordering via lgkmcnt).

        // phase B: PV.  A = own P^T rows (k), B = Vt rows (f).
        #pragma unroll
        for (int qc = 0; qc < 64; qc += 32) {
            bf16x8 pa[4], vbf[4];
            #pragma unroll
            for (int ks = 0; ks < 4; ++ks)
                pa[ks] = *(const bf16x8*)&pl[(w * 64 + ks * 16 + l15) * 72 + qc + g * 8];
            #pragma unroll
            for (int fb = 0; fb < 4; ++fb)
                vbf[fb] = *(const bf16x8*)&vt[(fb * 16 + l15) * 72 + qc + g * 8];
            #pragma unroll
            for (int ks = 0; ks < 4; ++ks)
                #pragma unroll
                for (int fb = 0; fb < 4; ++fb)
                    oacc[ks][fb] = MFMA16(pa[ks], vbf[fb], oacc[ks][fb]);
        }
    }

    // epilogue: bounce via pl (256 rows x 64) for coalesced bf16 stores
    __syncthreads();
    #pragma unroll
    for (int ks = 0; ks < 4; ++ks)
        #pragma unroll
        for (int fb = 0; fb < 4; ++fb)
            #pragma unroll
            for (int r = 0; r < 4; ++r)
                pl[(w * 64 + ks * 16 + g * 4 + r) * 72 + fb * 16 + l15] =
                    f2bfn(oacc[ks][fb][r]);
    __syncthreads();
    {
        short* O = qh ? O4b : O4a;
        short* o = O + ((size_t)bh * Sc + k0 + t) * Fc;
        #pragma unroll
        for (int j = 0; j < 64; j += 8)
            *(bf16x8*)&o[j] = *(const bf16x8*)&pl[t * 72 + j];
    }
}

// ---------------------------------------------------------------------------
// K4: out(fp32) = (O4a + O4b) @ Wo [r12 verbatim]. NT, dbuf, partial-sum in
// A-staging. m-tile 128 (msub=2). grid (32, 16), 256 thr.
// ---------------------------------------------------------------------------
__global__ __launch_bounds__(256) void outgemm_kernel(
    const short* __restrict__ Aa, const short* __restrict__ Ab,
    const short* __restrict__ WoT, float* __restrict__ out)
{
    const int m0 = blockIdx.x * 128, n0 = blockIdx.y * 64;

    __shared__ short asA[128 * 72], asB[128 * 72];
    __shared__ short wsA[64 * 72],  wsB[64 * 72];

    const int t = threadIdx.x, lane = t & 63, w = t >> 6;
    const int l15 = lane & 15, g = lane >> 4;
    const int ar = t >> 1, ac = (t & 1) * 32;
    const int wr = t >> 2, wc = (t & 3) * 16;

    bf16x8 ag0[4], ag1[4], wg[2];
    auto gload = [&](int d0) {
        const short* s0 = &Aa[(size_t)(m0 + ar) * Dc + d0 + ac];
        const short* s1 = &Ab[(size_t)(m0 + ar) * Dc + d0 + ac];
        #pragma unroll
        for (int j = 0; j < 4; ++j) { ag0[j] = *(const bf16x8*)(s0 + 8 * j);
                                      ag1[j] = *(const bf16x8*)(s1 + 8 * j); }
        const short* ww = &WoT[(size_t)(n0 + wr) * Dc + d0 + wc];
        wg[0] = *(const bf16x8*)ww;
        wg[1] = *(const bf16x8*)(ww + 8);
    };
    auto swrite = [&](short* asD, short* wsD) {
        #pragma unroll
        for (int j = 0; j < 4; ++j) {
            bf16x8 r;
            #pragma unroll
            for (int i = 0; i < 8; ++i)
                r[i] = f2bfn(bf2f(ag0[j][i]) + bf2f(ag1[j][i]));
            *(bf16x8*)&asD[ar * 72 + ac + 8 * j] = r;
        }
        *(bf16x8*)&wsD[wr * 72 + wc]     = wg[0];
        *(bf16x8*)&wsD[wr * 72 + wc + 8] = wg[1];
    };

    f32x4 acc[2][4];
    #pragma unroll
    for (int i = 0; i < 2; ++i)
        #pragma unroll
        for (int j = 0; j < 4; ++j) acc[i][j] = (f32x4){0.f, 0.f, 0.f, 0.f};

    gload(0); swrite(asA, wsA); gload(64);

    auto half = [&](int d0, const short* asC, const short* wsC,
                    short* asN, short* wsN) {
        __syncthreads();
        if (d0 + 64 < Dc) swrite(asN, wsN);
        if (d0 + 128 < Dc) gload(d0 + 128);
        #pragma unroll
        for (int kc = 0; kc < 64; kc += 32) {
            bf16x8 afr[2], bfr[4];
            #pragma unroll
            for (int ms = 0; ms < 2; ++ms)
                afr[ms] = *(const bf16x8*)&asC[(w * 32 + ms * 16 + l15) * 72 + kc + g * 8];
            #pragma unroll
            for (int nb = 0; nb < 4; ++nb)
                bfr[nb] = *(const bf16x8*)&wsC[(nb * 16 + l15) * 72 + kc + g * 8];
            #pragma unroll
            for (int ms = 0; ms < 2; ++ms)
                #pragma unroll
                for (int nb = 0; nb < 4; ++nb)
                    acc[ms][nb] = MFMA16(afr[ms], bfr[nb], acc[ms][nb]);
        }
    };

    for (int d0 = 0; d0 < Dc; d0 += 128) {
        half(d0,      asA, wsA, asB, wsB);
        half(d0 + 64, asB, wsB, asA, wsA);
    }

    #pragma unroll
    for (int ms = 0; ms < 2; ++ms)
        #pragma unroll
        for (int nb = 0; nb < 4; ++nb)
            #pragma unroll
            for (int r = 0; r < 4; ++r)
                out[(size_t)(m0 + w * 32 + ms * 16 + g * 4 + r) * 1024
                    + n0 + nb * 16 + l15] = acc[ms][nb][r];
}

// ---------------------------------------------------------------------------
extern "C" void kernel_launch(void* const* d_in, const int* in_sizes, int n_in,
                              void* d_out, int out_size, void* d_ws, size_t ws_size,
                              hipStream_t stream) {
    (void)in_sizes; (void)n_in; (void)out_size; (void)ws_size;
    const float* q  = (const float*)d_in[0];
    const float* k  = (const float*)d_in[1];
    const float* v  = (const float*)d_in[2];
    const float* Wq = (const float*)d_in[3];
    const float* Wk = (const float*)d_in[4];
    const float* Wv = (const float*)d_in[5];
    const float* Wo = (const float*)d_in[6];
    float* out = (float*)d_out;

    // ws (shorts unless noted): Q | K | Vt | O4a | O4b (4M each)
    //   | WqT | WkT | WvT | WoT (1M each) | mrow f32 (64K)  => 48.25 MiB
    short* Qw  = (short*)d_ws;
    short* Kw  = Qw  + BHSF;
    short* Vt  = Kw  + BHSF;
    short* O4a = Vt  + BHSF;
    short* O4b = O4a + BHSF;
    short* WqT = O4b + BHSF;
    short* WkT = WqT + Hc * Dc * Fc;
    short* WvT = WkT + Hc * Dc * Fc;
    short* WoT = WvT + Hc * Dc * Fc;
    float* mw  = (float*)(WoT + Dc * Dc);

    tcvt_all_kernel<<<dim3(16, 1, 64), 256, 0, stream>>>(Wq, Wk, Wv, Wo,
                                                         WqT, WkT, WvT, WoT);
    proj_kernel<<<dim3(32, 8, 3), 256, 0, stream>>>(q, k, v, WqT, WkT, WvT,
                                                    Qw, Kw, Vt);
    stats_kernel<<<dim3(32, 16), 256, 0, stream>>>(Qw, Kw, mw);
    attn_kernel<<<dim3(32, 2, 8), 256, 0, stream>>>(Qw, Kw, Vt, mw, O4a, O4b);
    outgemm_kernel<<<dim3(32, 16), 256, 0, stream>>>(O4a, O4b, WoT, out);
}